// Round 9
// baseline (208.536 us; speedup 1.0000x reference)
//
#include <hip/hip_runtime.h>
#include <hip/hip_bf16.h>

#define NN 50000
#define NN_PAD 50176   // 784*64
#define NE 800000
#define NB2 784        // one 64-node GEMM tile per 64 consecutive nodes
#define NDS 64         // per-node esrc2 stride (deg ~ Poisson(16); P(>63) ~ 1e-19)

typedef __attribute__((ext_vector_type(8))) short short8;
typedef __attribute__((ext_vector_type(4))) float f32x4;
typedef __attribute__((ext_vector_type(2))) float f32x2;
typedef __attribute__((ext_vector_type(4))) unsigned int u32x4;
typedef __attribute__((ext_vector_type(2))) unsigned int u32x2;

__device__ __forceinline__ unsigned short f2bf(float f) {
    union { float f; unsigned u; } v; v.f = f;
    unsigned u = v.u;
    return (unsigned short)((u + 0x7fffu + ((u >> 16) & 1u)) >> 16);
}
__device__ __forceinline__ float bfu_lo(unsigned u) {
    union { unsigned u; float f; } v; v.u = u << 16; return v.f;
}
__device__ __forceinline__ float bfu_hi(unsigned u) {
    union { unsigned u; float f; } v; v.u = u & 0xffff0000u; return v.f;
}
// accumulate 8 fp8 values (one uint2) into acc[0..7]
__device__ __forceinline__ void acc_fp8(float* acc, uint2 q) {
    f32x2 a0 = __builtin_amdgcn_cvt_pk_f32_fp8(q.x, false);
    f32x2 a1 = __builtin_amdgcn_cvt_pk_f32_fp8(q.x, true);
    f32x2 a2 = __builtin_amdgcn_cvt_pk_f32_fp8(q.y, false);
    f32x2 a3 = __builtin_amdgcn_cvt_pk_f32_fp8(q.y, true);
    acc[0] += a0.x; acc[1] += a0.y; acc[2] += a1.x; acc[3] += a1.y;
    acc[4] += a2.x; acc[5] += a2.y; acc[6] += a3.x; acc[7] += a3.y;
}

// A_pk fragment-packed layout: tile t (64 rows), element (r, k):
//   ks=k>>5, lq=(k>>3)&3, j=k&7, mi=r>>4, lm=r&15
//   index = t*16384 + ((ks*4+mi)*64 + lm + 16*lq)*8 + j

// CSR-free edge index: esrc2[d*64 + pos] = s, pos from one global atomicAdd per
// edge (order-nondeterministic; accumulation order proven irrelevant in r4).
// ndeg[d] = true degree. No sort, no prefix scan, no pairs intermediate.

// ---- merged setup ----
// blocks [0,3125): edge scatter — one edge/thread, direct atomic placement
// blocks [3125,3189): pack W1/W2 into MFMA B-fragment order
// blocks [3189,9439): x -> fp8 gather table + A_pk self-columns (bf16, frag-packed)
__global__ void k_setup_part(const float* __restrict__ W1l, const float* __restrict__ W1r,
                             const float* __restrict__ W2l, const float* __restrict__ W2r,
                             unsigned short* __restrict__ W1pk, unsigned short* __restrict__ W2pk,
                             const float* __restrict__ x, unsigned short* __restrict__ Apk,
                             unsigned char* __restrict__ x_f8,
                             const int* __restrict__ src, const int* __restrict__ dst,
                             int* __restrict__ ndeg, unsigned short* __restrict__ esrc2) {
    int blk = blockIdx.x, t = threadIdx.x;
    if (blk < 3125) {
        int e = blk * 256 + t;              // NE = 3125*256 exactly
        int s = src[e], d = dst[e];
        int pos = atomicAdd(&ndeg[d], 1);
        if (pos < NDS) esrc2[(size_t)d * NDS + pos] = (unsigned short)s;
    } else if (blk < 3189) {
        int tid = (blk - 3125) * 256 + t;   // 0..16383
        int table = tid >> 13;              // 0: W1, 1: W2
        int r = tid & 8191;
        int lane = r & 63, ni = (r >> 6) & 3, ks = (r >> 8) & 7, g = r >> 11;
        int lm = lane & 15, lq = lane >> 4;
        int o = g * 64 + ni * 16 + lm;
        int k = ks * 32 + lq * 8;
        unsigned short v[8];
        if (table == 0) {                   // W1 = [W1l | W1r] K-concat
            if (k < 128) {
#pragma unroll
                for (int j = 0; j < 8; ++j) v[j] = f2bf(W1l[o * 128 + k + j]);
            } else {
#pragma unroll
                for (int j = 0; j < 8; ++j) v[j] = f2bf(W1r[o * 128 + k - 128 + j]);
            }
            *(uint4*)(W1pk + (size_t)r * 8) = *(const uint4*)v;
        } else {                            // W2 = [W2l ; W2r] out-stack
            if (o < 128) {
#pragma unroll
                for (int j = 0; j < 8; ++j) v[j] = f2bf(W2l[o * 256 + k + j]);
            } else {
#pragma unroll
                for (int j = 0; j < 8; ++j) v[j] = f2bf(W2r[(o - 128) * 256 + k + j]);
            }
            *(uint4*)(W2pk + (size_t)r * 8) = *(const uint4*)v;
        }
    } else {
        int gid = (blk - 3189) * 256 + t;   // NN*32 threads exactly
        int n = gid >> 5, c = gid & 31;     // self cols k = 128 + c*4 .. +3
        f32x4 v = __builtin_nontemporal_load((const f32x4*)x + (size_t)n * 32 + c);
        unsigned short o[4];
        o[0] = f2bf(v[0]); o[1] = f2bf(v[1]); o[2] = f2bf(v[2]); o[3] = f2bf(v[3]);
        int k = 128 + c * 4;
        int ks = k >> 5, lq = (k >> 3) & 3, j0 = k & 7;
        int tile = n >> 6, r = n & 63, mi = r >> 4, lm = r & 15;
        *(u32x2*)(Apk + (size_t)tile * 16384 +
                  ((size_t)((ks * 4 + mi) * 64 + lm + 16 * lq)) * 8 + j0) = *(const u32x2*)o;
        unsigned p = (unsigned)__builtin_amdgcn_cvt_pk_fp8_f32(v[0], v[1], 0, false);
        p = (unsigned)__builtin_amdgcn_cvt_pk_fp8_f32(v[2], v[3], (int)p, true);
        *(unsigned*)(x_f8 + (size_t)n * 128 + c * 4) = p;
    }
}

// ============ layer-1 aggregation -> A_pk cols 0..127 (fragment-packed) ============
// No CSR build needed: per-node segments at fixed stride NDS. Full-occupancy
// r3-proven form: 16 threads/node, 8-deep independent gathers.
__global__ void k_agg1(const uint2* __restrict__ xf8, const int* __restrict__ ndeg,
                       const unsigned short* __restrict__ esrc2,
                       unsigned short* __restrict__ Apk) {
    int gid = blockIdx.x * blockDim.x + threadIdx.x;  // NN*16 threads exactly
    int n = gid >> 4, c = gid & 15;                   // cols k = c*8 .. +7
    int dgt = ndeg[n];
    int dg = min(dgt, NDS);
    const unsigned short* es = esrc2 + (size_t)n * NDS;
    float acc[8] = {0.f, 0.f, 0.f, 0.f, 0.f, 0.f, 0.f, 0.f};
    int i = 0;
    for (; i + 8 <= dg; i += 8) {
        int s0 = es[i],     s1 = es[i + 1];
        int s2 = es[i + 2], s3 = es[i + 3];
        int s4 = es[i + 4], s5 = es[i + 5];
        int s6 = es[i + 6], s7 = es[i + 7];
        uint2 q0 = xf8[(size_t)s0 * 16 + c];
        uint2 q1 = xf8[(size_t)s1 * 16 + c];
        uint2 q2 = xf8[(size_t)s2 * 16 + c];
        uint2 q3 = xf8[(size_t)s3 * 16 + c];
        uint2 q4 = xf8[(size_t)s4 * 16 + c];
        uint2 q5 = xf8[(size_t)s5 * 16 + c];
        uint2 q6 = xf8[(size_t)s6 * 16 + c];
        uint2 q7 = xf8[(size_t)s7 * 16 + c];
        acc_fp8(acc, q0); acc_fp8(acc, q1); acc_fp8(acc, q2); acc_fp8(acc, q3);
        acc_fp8(acc, q4); acc_fp8(acc, q5); acc_fp8(acc, q6); acc_fp8(acc, q7);
    }
    for (; i < dg; ++i)
        acc_fp8(acc, xf8[(size_t)es[i] * 16 + c]);
    float invd = 1.0f / (float)max(dgt, 1);
    unsigned short o[8];
#pragma unroll
    for (int j = 0; j < 8; ++j) o[j] = f2bf(acc[j] * invd);
    int ks = c >> 2, lq = c & 3;
    int tile = n >> 6, r = n & 63, mi = r >> 4, lm = r & 15;
    *(u32x4*)(Apk + (size_t)tile * 16384 +
              ((size_t)((ks * 4 + mi) * 64 + lm + 16 * lq)) * 8) = *(const u32x4*)o;
}

// ============ fused GEMM1(relu)+GEMM2 per 64-node tile, packed-A direct reads ============
// (r5 verbatim — verified absmax 0.0703125)
__global__ __launch_bounds__(256, 2) void k_gemm12(
        const unsigned short* __restrict__ Apk,
        const unsigned short* __restrict__ W1pk, const unsigned short* __restrict__ W2pk,
        const float* __restrict__ b1, const float* __restrict__ b2,
        unsigned char* __restrict__ y2f8, unsigned short* __restrict__ Sbf) {
    __shared__ unsigned short T[16384];   // 32 KB: h tile, then epilogue staging
    int t = threadIdx.x, blk = blockIdx.x;
    int wave = t >> 6, lane = t & 63;
    int lm = lane & 15, lq = lane >> 4;
    int pbase = lm * 4 + lq;

    short8 w[8][4];
    {
        const unsigned short* wb = W1pk + (size_t)wave * 16384;
#pragma unroll
        for (int ks = 0; ks < 8; ++ks)
#pragma unroll
            for (int ni = 0; ni < 4; ++ni)
                w[ks][ni] = *(const short8*)(wb + ((size_t)((ks * 4 + ni) * 64 + lane)) * 8);
    }

    const unsigned short* apk = Apk + (size_t)blk * 16384;
    f32x4 acc1[4][4];
#pragma unroll
    for (int mi = 0; mi < 4; ++mi)
#pragma unroll
        for (int ni = 0; ni < 4; ++ni) acc1[mi][ni] = (f32x4){0.f, 0.f, 0.f, 0.f};
#pragma unroll
    for (int ks = 0; ks < 8; ++ks) {
        short8 a[4];
#pragma unroll
        for (int mi = 0; mi < 4; ++mi)
            a[mi] = *(const short8*)(apk + ((size_t)((ks * 4 + mi) * 64 + lane)) * 8);
#pragma unroll
        for (int mi = 0; mi < 4; ++mi)
#pragma unroll
            for (int ni = 0; ni < 4; ++ni)
                acc1[mi][ni] = __builtin_amdgcn_mfma_f32_16x16x32_bf16(a[mi], w[ks][ni], acc1[mi][ni], 0, 0, 0);
    }

    {
        const unsigned short* wb = W2pk + (size_t)wave * 16384;
#pragma unroll
        for (int ks = 0; ks < 8; ++ks)
#pragma unroll
            for (int ni = 0; ni < 4; ++ni)
                w[ks][ni] = *(const short8*)(wb + ((size_t)((ks * 4 + ni) * 64 + lane)) * 8);
    }

#pragma unroll
    for (int ni = 0; ni < 4; ++ni) {
        int col = wave * 64 + ni * 16 + lm;
        float bv = b1[col];
        int ks = col >> 5;
        int la = (col & 31) >> 3, j = col & 7;
#pragma unroll
        for (int mi = 0; mi < 4; ++mi)
#pragma unroll
            for (int r = 0; r < 4; ++r) {
                float v = fmaxf(acc1[mi][ni][r] + bv, 0.0f);
                T[((size_t)((ks * 4 + mi) * 64 + (lq * 4 + r) * 4 + la)) * 8 + j] = f2bf(v);
            }
    }
    __syncthreads();

    f32x4 acc2[4][4];
#pragma unroll
    for (int mi = 0; mi < 4; ++mi)
#pragma unroll
        for (int ni = 0; ni < 4; ++ni) acc2[mi][ni] = (f32x4){0.f, 0.f, 0.f, 0.f};
#pragma unroll
    for (int ks = 0; ks < 8; ++ks) {
        short8 a[4];
#pragma unroll
        for (int mi = 0; mi < 4; ++mi)
            a[mi] = *(const short8*)(T + ((size_t)((ks * 4 + mi) * 64 + pbase)) * 8);
#pragma unroll
        for (int mi = 0; mi < 4; ++mi)
#pragma unroll
            for (int ni = 0; ni < 4; ++ni)
                acc2[mi][ni] = __builtin_amdgcn_mfma_f32_16x16x32_bf16(a[mi], w[ks][ni], acc2[mi][ni], 0, 0, 0);
    }
    __syncthreads();

    {
        unsigned char* T8 = (unsigned char*)T;
        unsigned short* T16 = (unsigned short*)T + 4096;
        if (wave < 2) {
#pragma unroll
            for (int ni = 0; ni < 4; ++ni) {
                int col = wave * 64 + ni * 16 + lm;
#pragma unroll
                for (int mi = 0; mi < 4; ++mi)
#pragma unroll
                    for (int r = 0; r < 4; ++r) {
                        int rl = mi * 16 + lq * 4 + r;
                        float v = acc2[mi][ni][r];
                        unsigned p = (unsigned)__builtin_amdgcn_cvt_pk_fp8_f32(v, v, 0, false);
                        T8[rl * 128 + col] = (unsigned char)(p & 0xff);
                    }
            }
        } else {
#pragma unroll
            for (int ni = 0; ni < 4; ++ni) {
                int col = (wave - 2) * 64 + ni * 16 + lm;
                float bv = b2[col];
#pragma unroll
                for (int mi = 0; mi < 4; ++mi)
#pragma unroll
                    for (int r = 0; r < 4; ++r) {
                        int rl = mi * 16 + lq * 4 + r;
                        T16[rl * 128 + col] = f2bf(acc2[mi][ni][r] + bv);
                    }
            }
        }
    }
    __syncthreads();

    {
        const uint4* Ty = (const uint4*)T;
        uint4* gy = (uint4*)(y2f8 + (size_t)blk * 64 * 128);
        gy[t] = Ty[t];
        gy[t + 256] = Ty[t + 256];
        const u32x4* Ts = (const u32x4*)((const char*)T + 8192);
        u32x4* gs = (u32x4*)(Sbf + (size_t)blk * 64 * 128);
#pragma unroll
        for (int i = 0; i < 4; ++i)
            __builtin_nontemporal_store(Ts[t + i * 256], &gs[t + i * 256]);
    }
}

// ============ output: out[n] = Sbf[n] + mean_nbr(y2f8)  (r5-verified form) ============
__global__ void k_agg_out(const uint2* __restrict__ yf8, const unsigned short* __restrict__ Sbf,
                          const int* __restrict__ ndeg,
                          const unsigned short* __restrict__ esrc2,
                          float* __restrict__ out) {
    int gid = blockIdx.x * blockDim.x + threadIdx.x;  // NN*16 threads exactly
    int n = gid >> 4, c = gid & 15;
    int dgt = ndeg[n];
    int dg = min(dgt, NDS);
    const unsigned short* es = esrc2 + (size_t)n * NDS;
    float acc[8] = {0.f, 0.f, 0.f, 0.f, 0.f, 0.f, 0.f, 0.f};
    int i = 0;
    for (; i + 8 <= dg; i += 8) {
        int s0 = es[i],     s1 = es[i + 1];
        int s2 = es[i + 2], s3 = es[i + 3];
        int s4 = es[i + 4], s5 = es[i + 5];
        int s6 = es[i + 6], s7 = es[i + 7];
        uint2 q0 = yf8[(size_t)s0 * 16 + c];
        uint2 q1 = yf8[(size_t)s1 * 16 + c];
        uint2 q2 = yf8[(size_t)s2 * 16 + c];
        uint2 q3 = yf8[(size_t)s3 * 16 + c];
        uint2 q4 = yf8[(size_t)s4 * 16 + c];
        uint2 q5 = yf8[(size_t)s5 * 16 + c];
        uint2 q6 = yf8[(size_t)s6 * 16 + c];
        uint2 q7 = yf8[(size_t)s7 * 16 + c];
        acc_fp8(acc, q0); acc_fp8(acc, q1); acc_fp8(acc, q2); acc_fp8(acc, q3);
        acc_fp8(acc, q4); acc_fp8(acc, q5); acc_fp8(acc, q6); acc_fp8(acc, q7);
    }
    for (; i < dg; ++i)
        acc_fp8(acc, yf8[(size_t)es[i] * 16 + c]);
    float invd = 1.0f / (float)max(dgt, 1);
    u32x4 sv = __builtin_nontemporal_load((const u32x4*)Sbf + (size_t)n * 16 + c);
    f32x4 o0, o1;
    o0[0] = bfu_lo(sv[0]) + acc[0] * invd; o0[1] = bfu_hi(sv[0]) + acc[1] * invd;
    o0[2] = bfu_lo(sv[1]) + acc[2] * invd; o0[3] = bfu_hi(sv[1]) + acc[3] * invd;
    o1[0] = bfu_lo(sv[2]) + acc[4] * invd; o1[1] = bfu_hi(sv[2]) + acc[5] * invd;
    o1[2] = bfu_lo(sv[3]) + acc[6] * invd; o1[3] = bfu_hi(sv[3]) + acc[7] * invd;
    f32x4* op = (f32x4*)(out + (size_t)n * 128 + c * 8);
    __builtin_nontemporal_store(o0, op);
    __builtin_nontemporal_store(o1, op + 1);
}

extern "C" void kernel_launch(void* const* d_in, const int* in_sizes, int n_in,
                              void* d_out, int out_size, void* d_ws, size_t ws_size,
                              hipStream_t stream) {
    const float* x   = (const float*)d_in[0];
    const int*   ei  = (const int*)d_in[1];
    const int*   src = ei;
    const int*   dst = ei + NE;
    const float* W1l = (const float*)d_in[2];
    const float* b1  = (const float*)d_in[3];
    const float* W1r = (const float*)d_in[4];
    const float* W2l = (const float*)d_in[5];
    const float* b2  = (const float*)d_in[6];
    const float* W2r = (const float*)d_in[7];
    float* out = (float*)d_out;

    // workspace layout (~58.3 MB):
    char* ws = (char*)d_ws;
    int* ndeg             = (int*)(ws + 0);                    // [NN_PAD] true degrees
    unsigned short* esrc2 = (unsigned short*)(ws + 204800);    // [NN_PAD*64] 6.42 MB
    unsigned char* x_f8   = (unsigned char*)(ws + 6635520);    // [NN,128] fp8 6.4 MB
    unsigned short* Sbf   = (unsigned short*)(ws + 13041664);  // [NN_PAD,128] bf16 12.85 MB
    unsigned char* y2f8   = (unsigned char*)(ws + 25890816);   // [NN_PAD,128] fp8 6.42 MB
    unsigned short* Apk   = (unsigned short*)(ws + 32317440);  // [NN_PAD,256] bf16 frag-packed
    unsigned short* W1pk  = (unsigned short*)(ws + 58011648);  // [65536] 131 KB frag-packed
    unsigned short* W2pk  = (unsigned short*)(ws + 58142720);  // [65536] 131 KB frag-packed

    hipMemsetAsync(ndeg, 0, NN_PAD * 4, stream);
    k_setup_part<<<9439, 256, 0, stream>>>(W1l, W1r, W2l, W2r, W1pk, W2pk,
                                           x, Apk, x_f8, src, dst, ndeg, esrc2);
    k_agg1<<<NN * 16 / 256, 256, 0, stream>>>((const uint2*)x_f8, ndeg, esrc2, Apk);
    k_gemm12<<<NB2, 256, 0, stream>>>(Apk, W1pk, W2pk, b1, b2, y2f8, Sbf);
    k_agg_out<<<NN * 16 / 256, 256, 0, stream>>>((const uint2*)y2f8, Sbf,
                                                 ndeg, esrc2, out);
}

// Round 10
// 180.079 us; speedup vs baseline: 1.1580x; 1.1580x over previous
//
#include <hip/hip_runtime.h>
#include <hip/hip_bf16.h>

#define NN 50000
#define NN_PAD 50176   // 784*64
#define NE 800000
#define NB 196         // pass-A partition blocks (edge ranges)
#define NB2 784        // buckets = dst>>6, one 64-node GEMM tile per bucket
#define CAP2 1536      // per-bucket pair capacity (mean 1020, sd ~32; 16 sigma)
#define EPB 4096       // edges per pass-A block

typedef __attribute__((ext_vector_type(8))) short short8;
typedef __attribute__((ext_vector_type(4))) float f32x4;
typedef __attribute__((ext_vector_type(2))) float f32x2;
typedef __attribute__((ext_vector_type(4))) unsigned int u32x4;
typedef __attribute__((ext_vector_type(2))) unsigned int u32x2;

__device__ __forceinline__ unsigned short f2bf(float f) {
    union { float f; unsigned u; } v; v.f = f;
    unsigned u = v.u;
    return (unsigned short)((u + 0x7fffu + ((u >> 16) & 1u)) >> 16);
}
__device__ __forceinline__ float bfu_lo(unsigned u) {
    union { unsigned u; float f; } v; v.u = u << 16; return v.f;
}
__device__ __forceinline__ float bfu_hi(unsigned u) {
    union { unsigned u; float f; } v; v.u = u & 0xffff0000u; return v.f;
}
// accumulate 8 fp8 values (one uint2) into acc[0..7]
__device__ __forceinline__ void acc_fp8(float* acc, uint2 q) {
    f32x2 a0 = __builtin_amdgcn_cvt_pk_f32_fp8(q.x, false);
    f32x2 a1 = __builtin_amdgcn_cvt_pk_f32_fp8(q.x, true);
    f32x2 a2 = __builtin_amdgcn_cvt_pk_f32_fp8(q.y, false);
    f32x2 a3 = __builtin_amdgcn_cvt_pk_f32_fp8(q.y, true);
    acc[0] += a0.x; acc[1] += a0.y; acc[2] += a1.x; acc[3] += a1.y;
    acc[4] += a2.x; acc[5] += a2.y; acc[6] += a3.x; acc[7] += a3.y;
}

// A_pk fragment-packed layout: tile t (64 rows), element (r, k):
//   ks=k>>5, lq=(k>>3)&3, j=k&7, mi=r>>4, lm=r&15
//   index = t*16384 + ((ks*4+mi)*64 + lm + 16*lq)*8 + j

// meta[n] = esrc_start | (deg << 21); esrc is bucket-strided (b*CAP2 + local),
// so no global prefix scan is needed anywhere.

// ---- merged setup + edge-partition ----
// blocks [0,196): edge partition into 784 dst>>6 buckets (pairs = (s<<6)|(d&63))
// blocks [196,260): pack W1/W2 into MFMA B-fragment order
// blocks [260,6510): x -> fp8 gather table + A_pk self-columns (bf16, frag-packed)
__global__ void k_setup_part(const float* __restrict__ W1l, const float* __restrict__ W1r,
                             const float* __restrict__ W2l, const float* __restrict__ W2r,
                             unsigned short* __restrict__ W1pk, unsigned short* __restrict__ W2pk,
                             const float* __restrict__ x, unsigned short* __restrict__ Apk,
                             unsigned char* __restrict__ x_f8,
                             const int* __restrict__ src, const int* __restrict__ dst,
                             int* __restrict__ gcursor, unsigned* __restrict__ pairs) {
    int blk = blockIdx.x, t = threadIdx.x;
    if (blk < NB) {
        __shared__ int cnt[NB2];
        __shared__ int cur[NB2];
        __shared__ int base[NB2];
        for (int k = t; k < NB2; k += 256) { cnt[k] = 0; cur[k] = 0; }
        __syncthreads();
        int e0 = blk * EPB;
        int eend = min(e0 + EPB, NE);
        for (int e = e0 + t; e < eend; e += 256)
            atomicAdd(&cnt[dst[e] >> 6], 1);
        __syncthreads();
        for (int k = t; k < NB2; k += 256)
            if (cnt[k] > 0) base[k] = k * CAP2 + atomicAdd(&gcursor[k], cnt[k]);
        __syncthreads();
        for (int e = e0 + t; e < eend; e += 256) {
            int s = src[e], d = dst[e];
            int bk = d >> 6;
            int pos = base[bk] + atomicAdd(&cur[bk], 1);
            if (pos < (bk + 1) * CAP2) pairs[pos] = ((unsigned)s << 6) | (unsigned)(d & 63);
        }
    } else if (blk < 260) {
        int tid = (blk - 196) * 256 + t;    // 0..16383
        int table = tid >> 13;              // 0: W1, 1: W2
        int r = tid & 8191;
        int lane = r & 63, ni = (r >> 6) & 3, ks = (r >> 8) & 7, g = r >> 11;
        int lm = lane & 15, lq = lane >> 4;
        int o = g * 64 + ni * 16 + lm;
        int k = ks * 32 + lq * 8;
        unsigned short v[8];
        if (table == 0) {                   // W1 = [W1l | W1r] K-concat
            if (k < 128) {
#pragma unroll
                for (int j = 0; j < 8; ++j) v[j] = f2bf(W1l[o * 128 + k + j]);
            } else {
#pragma unroll
                for (int j = 0; j < 8; ++j) v[j] = f2bf(W1r[o * 128 + k - 128 + j]);
            }
            *(uint4*)(W1pk + (size_t)r * 8) = *(const uint4*)v;
        } else {                            // W2 = [W2l ; W2r] out-stack
            if (o < 128) {
#pragma unroll
                for (int j = 0; j < 8; ++j) v[j] = f2bf(W2l[o * 256 + k + j]);
            } else {
#pragma unroll
                for (int j = 0; j < 8; ++j) v[j] = f2bf(W2r[(o - 128) * 256 + k + j]);
            }
            *(uint4*)(W2pk + (size_t)r * 8) = *(const uint4*)v;
        }
    } else {
        int gid = (blk - 260) * 256 + t;    // NN*32 threads exactly
        int n = gid >> 5, c = gid & 31;     // self cols k = 128 + c*4 .. +3
        f32x4 v = __builtin_nontemporal_load((const f32x4*)x + (size_t)n * 32 + c);
        unsigned short o[4];
        o[0] = f2bf(v[0]); o[1] = f2bf(v[1]); o[2] = f2bf(v[2]); o[3] = f2bf(v[3]);
        int k = 128 + c * 4;
        int ks = k >> 5, lq = (k >> 3) & 3, j0 = k & 7;
        int tile = n >> 6, r = n & 63, mi = r >> 4, lm = r & 15;
        *(u32x2*)(Apk + (size_t)tile * 16384 +
                  ((size_t)((ks * 4 + mi) * 64 + lm + 16 * lq)) * 8 + j0) = *(const u32x2*)o;
        unsigned p = (unsigned)__builtin_amdgcn_cvt_pk_fp8_f32(v[0], v[1], 0, false);
        p = (unsigned)__builtin_amdgcn_cvt_pk_fp8_f32(v[2], v[3], (int)p, true);
        *(unsigned*)(x_f8 + (size_t)n * 128 + c * 4) = p;
    }
}

// ============ fused CSR build + layer-1 aggregation per 64-node bucket ============
// Block b: counting-sort bucket b's pairs in LDS (int atomics only), persist
// esrc/meta for k_agg_out, then aggregate its 64 nodes r3-style: 16 threads per
// node, src IDs from LDS, 8-deep independent gathers, write Apk cols 0..127.
// ~10 KB LDS, 512 threads -> ~4 blocks/CU = full occupancy for latency hiding.
__global__ __launch_bounds__(512) void k_build_agg1(
        const int* __restrict__ gcursor, const unsigned* __restrict__ pairs,
        const uint2* __restrict__ xf8, unsigned short* __restrict__ esrc,
        unsigned* __restrict__ meta, unsigned short* __restrict__ Apk) {
    __shared__ unsigned lp[CAP2];          // 6 KB pair cache
    __shared__ unsigned short lsrc[CAP2];  // 3 KB sorted src ids
    __shared__ int ldeg[64];
    __shared__ int lcur[64];
    __shared__ int lstart[64];
    int b = blockIdx.x, t = threadIdx.x;
    if (t < 64) ldeg[t] = 0;
    __syncthreads();
    int cnt = min(gcursor[b], CAP2);
    const unsigned* pb = pairs + (size_t)b * CAP2;
    for (int e = t; e < cnt; e += 512) {
        unsigned p = pb[e];
        lp[e] = p;
        atomicAdd(&ldeg[p & 63u], 1);      // int LDS atomic: native ds_add
    }
    __syncthreads();
    if (t < 64) {                          // 64-wide exclusive scan (wave 0, broadcast reads)
        int s = 0;
        for (int j = 0; j < t; ++j) s += ldeg[j];
        lstart[t] = s; lcur[t] = s;
    }
    __syncthreads();
    for (int e = t; e < cnt; e += 512) {
        unsigned p = lp[e];
        int pos = atomicAdd(&lcur[p & 63u], 1);
        lsrc[pos] = (unsigned short)(p >> 6);
    }
    __syncthreads();
    // persist CSR for k_agg_out (bucket-strided esrc; no compaction)
    for (int e = t; e < cnt; e += 512) esrc[(size_t)b * CAP2 + e] = lsrc[e];
    if (t < 64) {
        int node = b * 64 + t;
        if (node < NN)
            meta[node] = ((unsigned)(b * CAP2 + lstart[t])) | ((unsigned)ldeg[t] << 21);
    }
    // ---- aggregation: 16 threads/node, 32 nodes per round, 2 rounds ----
    int c = t & 15;
#pragma unroll
    for (int rr = 0; rr < 2; ++rr) {
        int nl = rr * 32 + (t >> 4);
        int st = lstart[nl], dg = ldeg[nl];
        float acc[8] = {0.f, 0.f, 0.f, 0.f, 0.f, 0.f, 0.f, 0.f};
        int i = 0;
        for (; i + 8 <= dg; i += 8) {
            int s0 = lsrc[st + i],     s1 = lsrc[st + i + 1];
            int s2 = lsrc[st + i + 2], s3 = lsrc[st + i + 3];
            int s4 = lsrc[st + i + 4], s5 = lsrc[st + i + 5];
            int s6 = lsrc[st + i + 6], s7 = lsrc[st + i + 7];
            uint2 q0 = xf8[(size_t)s0 * 16 + c];
            uint2 q1 = xf8[(size_t)s1 * 16 + c];
            uint2 q2 = xf8[(size_t)s2 * 16 + c];
            uint2 q3 = xf8[(size_t)s3 * 16 + c];
            uint2 q4 = xf8[(size_t)s4 * 16 + c];
            uint2 q5 = xf8[(size_t)s5 * 16 + c];
            uint2 q6 = xf8[(size_t)s6 * 16 + c];
            uint2 q7 = xf8[(size_t)s7 * 16 + c];
            acc_fp8(acc, q0); acc_fp8(acc, q1); acc_fp8(acc, q2); acc_fp8(acc, q3);
            acc_fp8(acc, q4); acc_fp8(acc, q5); acc_fp8(acc, q6); acc_fp8(acc, q7);
        }
        for (; i < dg; ++i) {
            int s = lsrc[st + i];
            acc_fp8(acc, xf8[(size_t)s * 16 + c]);
        }
        float invd = 1.0f / (float)max(dg, 1);
        unsigned short o[8];
#pragma unroll
        for (int j = 0; j < 8; ++j) o[j] = f2bf(acc[j] * invd);
        int ks = c >> 2, lq = c & 3;
        int mi = nl >> 4, lm = nl & 15;
        *(u32x4*)(Apk + (size_t)b * 16384 +
                  ((size_t)((ks * 4 + mi) * 64 + lm + 16 * lq)) * 8) = *(const u32x4*)o;
    }
}

// ============ fused GEMM1(relu)+GEMM2 per 64-node tile, packed-A direct reads ============
// (unchanged — verified absmax 0.0703125)
__global__ __launch_bounds__(256, 2) void k_gemm12(
        const unsigned short* __restrict__ Apk,
        const unsigned short* __restrict__ W1pk, const unsigned short* __restrict__ W2pk,
        const float* __restrict__ b1, const float* __restrict__ b2,
        unsigned char* __restrict__ y2f8, unsigned short* __restrict__ Sbf) {
    __shared__ unsigned short T[16384];   // 32 KB: h tile, then epilogue staging
    int t = threadIdx.x, blk = blockIdx.x;
    int wave = t >> 6, lane = t & 63;
    int lm = lane & 15, lq = lane >> 4;
    int pbase = lm * 4 + lq;

    short8 w[8][4];
    {
        const unsigned short* wb = W1pk + (size_t)wave * 16384;
#pragma unroll
        for (int ks = 0; ks < 8; ++ks)
#pragma unroll
            for (int ni = 0; ni < 4; ++ni)
                w[ks][ni] = *(const short8*)(wb + ((size_t)((ks * 4 + ni) * 64 + lane)) * 8);
    }

    const unsigned short* apk = Apk + (size_t)blk * 16384;
    f32x4 acc1[4][4];
#pragma unroll
    for (int mi = 0; mi < 4; ++mi)
#pragma unroll
        for (int ni = 0; ni < 4; ++ni) acc1[mi][ni] = (f32x4){0.f, 0.f, 0.f, 0.f};
#pragma unroll
    for (int ks = 0; ks < 8; ++ks) {
        short8 a[4];
#pragma unroll
        for (int mi = 0; mi < 4; ++mi)
            a[mi] = *(const short8*)(apk + ((size_t)((ks * 4 + mi) * 64 + lane)) * 8);
#pragma unroll
        for (int mi = 0; mi < 4; ++mi)
#pragma unroll
            for (int ni = 0; ni < 4; ++ni)
                acc1[mi][ni] = __builtin_amdgcn_mfma_f32_16x16x32_bf16(a[mi], w[ks][ni], acc1[mi][ni], 0, 0, 0);
    }

    {
        const unsigned short* wb = W2pk + (size_t)wave * 16384;
#pragma unroll
        for (int ks = 0; ks < 8; ++ks)
#pragma unroll
            for (int ni = 0; ni < 4; ++ni)
                w[ks][ni] = *(const short8*)(wb + ((size_t)((ks * 4 + ni) * 64 + lane)) * 8);
    }

#pragma unroll
    for (int ni = 0; ni < 4; ++ni) {
        int col = wave * 64 + ni * 16 + lm;
        float bv = b1[col];
        int ks = col >> 5;
        int la = (col & 31) >> 3, j = col & 7;
#pragma unroll
        for (int mi = 0; mi < 4; ++mi)
#pragma unroll
            for (int r = 0; r < 4; ++r) {
                float v = fmaxf(acc1[mi][ni][r] + bv, 0.0f);
                T[((size_t)((ks * 4 + mi) * 64 + (lq * 4 + r) * 4 + la)) * 8 + j] = f2bf(v);
            }
    }
    __syncthreads();

    f32x4 acc2[4][4];
#pragma unroll
    for (int mi = 0; mi < 4; ++mi)
#pragma unroll
        for (int ni = 0; ni < 4; ++ni) acc2[mi][ni] = (f32x4){0.f, 0.f, 0.f, 0.f};
#pragma unroll
    for (int ks = 0; ks < 8; ++ks) {
        short8 a[4];
#pragma unroll
        for (int mi = 0; mi < 4; ++mi)
            a[mi] = *(const short8*)(T + ((size_t)((ks * 4 + mi) * 64 + pbase)) * 8);
#pragma unroll
        for (int mi = 0; mi < 4; ++mi)
#pragma unroll
            for (int ni = 0; ni < 4; ++ni)
                acc2[mi][ni] = __builtin_amdgcn_mfma_f32_16x16x32_bf16(a[mi], w[ks][ni], acc2[mi][ni], 0, 0, 0);
    }
    __syncthreads();

    {
        unsigned char* T8 = (unsigned char*)T;
        unsigned short* T16 = (unsigned short*)T + 4096;
        if (wave < 2) {
#pragma unroll
            for (int ni = 0; ni < 4; ++ni) {
                int col = wave * 64 + ni * 16 + lm;
#pragma unroll
                for (int mi = 0; mi < 4; ++mi)
#pragma unroll
                    for (int r = 0; r < 4; ++r) {
                        int rl = mi * 16 + lq * 4 + r;
                        float v = acc2[mi][ni][r];
                        unsigned p = (unsigned)__builtin_amdgcn_cvt_pk_fp8_f32(v, v, 0, false);
                        T8[rl * 128 + col] = (unsigned char)(p & 0xff);
                    }
            }
        } else {
#pragma unroll
            for (int ni = 0; ni < 4; ++ni) {
                int col = (wave - 2) * 64 + ni * 16 + lm;
                float bv = b2[col];
#pragma unroll
                for (int mi = 0; mi < 4; ++mi)
#pragma unroll
                    for (int r = 0; r < 4; ++r) {
                        int rl = mi * 16 + lq * 4 + r;
                        T16[rl * 128 + col] = f2bf(acc2[mi][ni][r] + bv);
                    }
            }
        }
    }
    __syncthreads();

    {
        const uint4* Ty = (const uint4*)T;
        uint4* gy = (uint4*)(y2f8 + (size_t)blk * 64 * 128);
        gy[t] = Ty[t];
        gy[t + 256] = Ty[t + 256];
        const u32x4* Ts = (const u32x4*)((const char*)T + 8192);
        u32x4* gs = (u32x4*)(Sbf + (size_t)blk * 64 * 128);
#pragma unroll
        for (int i = 0; i < 4; ++i)
            __builtin_nontemporal_store(Ts[t + i * 256], &gs[t + i * 256]);
    }
}

// ============ output: out[n] = Sbf[n] + mean_nbr(y2f8)  (r3-verified form) ============
__global__ void k_agg_out(const uint2* __restrict__ yf8, const unsigned short* __restrict__ Sbf,
                          const unsigned* __restrict__ meta,
                          const unsigned short* __restrict__ esrc,
                          float* __restrict__ out) {
    int gid = blockIdx.x * blockDim.x + threadIdx.x;  // NN*16 threads exactly
    int n = gid >> 4, c = gid & 15;
    unsigned mt = meta[n];
    int st = (int)(mt & 0x1FFFFFu), dg = (int)(mt >> 21);
    float acc[8] = {0.f, 0.f, 0.f, 0.f, 0.f, 0.f, 0.f, 0.f};
    int i = 0;
    for (; i + 8 <= dg; i += 8) {
        int s0 = esrc[st + i],     s1 = esrc[st + i + 1];
        int s2 = esrc[st + i + 2], s3 = esrc[st + i + 3];
        int s4 = esrc[st + i + 4], s5 = esrc[st + i + 5];
        int s6 = esrc[st + i + 6], s7 = esrc[st + i + 7];
        uint2 q0 = yf8[(size_t)s0 * 16 + c];
        uint2 q1 = yf8[(size_t)s1 * 16 + c];
        uint2 q2 = yf8[(size_t)s2 * 16 + c];
        uint2 q3 = yf8[(size_t)s3 * 16 + c];
        uint2 q4 = yf8[(size_t)s4 * 16 + c];
        uint2 q5 = yf8[(size_t)s5 * 16 + c];
        uint2 q6 = yf8[(size_t)s6 * 16 + c];
        uint2 q7 = yf8[(size_t)s7 * 16 + c];
        acc_fp8(acc, q0); acc_fp8(acc, q1); acc_fp8(acc, q2); acc_fp8(acc, q3);
        acc_fp8(acc, q4); acc_fp8(acc, q5); acc_fp8(acc, q6); acc_fp8(acc, q7);
    }
    for (; i < dg; ++i) {
        int s = esrc[st + i];
        acc_fp8(acc, yf8[(size_t)s * 16 + c]);
    }
    float invd = 1.0f / (float)max(dg, 1);
    u32x4 sv = __builtin_nontemporal_load((const u32x4*)Sbf + (size_t)n * 16 + c);
    f32x4 o0, o1;
    o0[0] = bfu_lo(sv[0]) + acc[0] * invd; o0[1] = bfu_hi(sv[0]) + acc[1] * invd;
    o0[2] = bfu_lo(sv[1]) + acc[2] * invd; o0[3] = bfu_hi(sv[1]) + acc[3] * invd;
    o1[0] = bfu_lo(sv[2]) + acc[4] * invd; o1[1] = bfu_hi(sv[2]) + acc[5] * invd;
    o1[2] = bfu_lo(sv[3]) + acc[6] * invd; o1[3] = bfu_hi(sv[3]) + acc[7] * invd;
    f32x4* op = (f32x4*)(out + (size_t)n * 128 + c * 8);
    __builtin_nontemporal_store(o0, op);
    __builtin_nontemporal_store(o1, op + 1);
}

extern "C" void kernel_launch(void* const* d_in, const int* in_sizes, int n_in,
                              void* d_out, int out_size, void* d_ws, size_t ws_size,
                              hipStream_t stream) {
    const float* x   = (const float*)d_in[0];
    const int*   ei  = (const int*)d_in[1];
    const int*   src = ei;
    const int*   dst = ei + NE;
    const float* W1l = (const float*)d_in[2];
    const float* b1  = (const float*)d_in[3];
    const float* W1r = (const float*)d_in[4];
    const float* W2l = (const float*)d_in[5];
    const float* b2  = (const float*)d_in[6];
    const float* W2r = (const float*)d_in[7];
    float* out = (float*)d_out;

    // workspace layout (~59 MB):
    char* ws = (char*)d_ws;
    int* gcursor          = (int*)(ws + 0);                    // [784] bucket counts
    unsigned* meta        = (unsigned*)(ws + 4096);            // [NN_PAD] start|deg<<21
    unsigned* pairs       = (unsigned*)(ws + 204800);          // [784*1536] 4.8 MB
    unsigned short* esrc  = (unsigned short*)(ws + 5021696);   // [784*1536] 2.4 MB
    unsigned char* x_f8   = (unsigned char*)(ws + 7430144);    // [NN,128] fp8 6.4 MB
    unsigned short* Sbf   = (unsigned short*)(ws + 13830144);  // [NN_PAD,128] bf16 12.85 MB
    unsigned char* y2f8   = (unsigned char*)(ws + 26675200);   // [NN_PAD,128] fp8 6.42 MB
    unsigned short* Apk   = (unsigned short*)(ws + 33097728);  // [NN_PAD,256] bf16 frag-packed
    unsigned short* W1pk  = (unsigned short*)(ws + 58787840);  // [65536] 131 KB frag-packed
    unsigned short* W2pk  = (unsigned short*)(ws + 58918912);  // [65536] 131 KB frag-packed

    hipMemsetAsync(gcursor, 0, 4096, stream);
    k_setup_part<<<6510, 256, 0, stream>>>(W1l, W1r, W2l, W2r, W1pk, W2pk,
                                           x, Apk, x_f8, src, dst, gcursor, pairs);
    k_build_agg1<<<NB2, 512, 0, stream>>>(gcursor, pairs, (const uint2*)x_f8,
                                          esrc, meta, Apk);
    k_gemm12<<<NB2, 256, 0, stream>>>(Apk, W1pk, W2pk, b1, b2, y2f8, Sbf);
    k_agg_out<<<NN * 16 / 256, 256, 0, stream>>>((const uint2*)y2f8, Sbf,
                                                 meta, esrc, out);
}

// Round 11
// 180.028 us; speedup vs baseline: 1.1584x; 1.0003x over previous
//
#include <hip/hip_runtime.h>
#include <hip/hip_bf16.h>

#define NN 50000
#define NN_PAD 50176   // 784*64
#define NE 800000
#define NB 196         // pass-A partition blocks (edge ranges)
#define NB2 784        // buckets = dst>>6, one 64-node GEMM tile per bucket
#define CAP2 1536      // per-bucket pair capacity (mean 1020, sd ~32; 16 sigma)
#define EPB 4096       // edges per pass-A block

typedef __attribute__((ext_vector_type(8))) short short8;
typedef __attribute__((ext_vector_type(4))) float f32x4;
typedef __attribute__((ext_vector_type(2))) float f32x2;
typedef __attribute__((ext_vector_type(4))) unsigned int u32x4;
typedef __attribute__((ext_vector_type(2))) unsigned int u32x2;

__device__ __forceinline__ unsigned short f2bf(float f) {
    union { float f; unsigned u; } v; v.f = f;
    unsigned u = v.u;
    return (unsigned short)((u + 0x7fffu + ((u >> 16) & 1u)) >> 16);
}
__device__ __forceinline__ float bfu_lo(unsigned u) {
    union { unsigned u; float f; } v; v.u = u << 16; return v.f;
}
__device__ __forceinline__ float bfu_hi(unsigned u) {
    union { unsigned u; float f; } v; v.u = u & 0xffff0000u; return v.f;
}
// accumulate 16 fp8 values (one uint4 = 16B row chunk) into acc[0..15].
// Column order matches the old 2x uint2 path exactly -> bit-identical sums.
__device__ __forceinline__ void acc_fp8x4(float* acc, uint4 q) {
    f32x2 a0 = __builtin_amdgcn_cvt_pk_f32_fp8(q.x, false);
    f32x2 a1 = __builtin_amdgcn_cvt_pk_f32_fp8(q.x, true);
    f32x2 a2 = __builtin_amdgcn_cvt_pk_f32_fp8(q.y, false);
    f32x2 a3 = __builtin_amdgcn_cvt_pk_f32_fp8(q.y, true);
    f32x2 a4 = __builtin_amdgcn_cvt_pk_f32_fp8(q.z, false);
    f32x2 a5 = __builtin_amdgcn_cvt_pk_f32_fp8(q.z, true);
    f32x2 a6 = __builtin_amdgcn_cvt_pk_f32_fp8(q.w, false);
    f32x2 a7 = __builtin_amdgcn_cvt_pk_f32_fp8(q.w, true);
    acc[0]  += a0.x; acc[1]  += a0.y; acc[2]  += a1.x; acc[3]  += a1.y;
    acc[4]  += a2.x; acc[5]  += a2.y; acc[6]  += a3.x; acc[7]  += a3.y;
    acc[8]  += a4.x; acc[9]  += a4.y; acc[10] += a5.x; acc[11] += a5.y;
    acc[12] += a6.x; acc[13] += a6.y; acc[14] += a7.x; acc[15] += a7.y;
}

// A_pk fragment-packed layout: tile t (64 rows), element (r, k):
//   ks=k>>5, lq=(k>>3)&3, j=k&7, mi=r>>4, lm=r&15
//   index = t*16384 + ((ks*4+mi)*64 + lm + 16*lq)*8 + j

// meta[n] = esrc_start | (deg << 21); esrc is bucket-strided (b*CAP2 + local),
// so no global prefix scan is needed anywhere.

// ---- merged setup + edge-partition (r5/r10 verbatim) ----
// blocks [0,196): edge partition into 784 dst>>6 buckets (pairs = (s<<6)|(d&63))
// blocks [196,260): pack W1/W2 into MFMA B-fragment order
// blocks [260,6510): x -> fp8 gather table + A_pk self-columns (bf16, frag-packed)
__global__ void k_setup_part(const float* __restrict__ W1l, const float* __restrict__ W1r,
                             const float* __restrict__ W2l, const float* __restrict__ W2r,
                             unsigned short* __restrict__ W1pk, unsigned short* __restrict__ W2pk,
                             const float* __restrict__ x, unsigned short* __restrict__ Apk,
                             unsigned char* __restrict__ x_f8,
                             const int* __restrict__ src, const int* __restrict__ dst,
                             int* __restrict__ gcursor, unsigned* __restrict__ pairs) {
    int blk = blockIdx.x, t = threadIdx.x;
    if (blk < NB) {
        __shared__ int cnt[NB2];
        __shared__ int cur[NB2];
        __shared__ int base[NB2];
        for (int k = t; k < NB2; k += 256) { cnt[k] = 0; cur[k] = 0; }
        __syncthreads();
        int e0 = blk * EPB;
        int eend = min(e0 + EPB, NE);
        for (int e = e0 + t; e < eend; e += 256)
            atomicAdd(&cnt[dst[e] >> 6], 1);
        __syncthreads();
        for (int k = t; k < NB2; k += 256)
            if (cnt[k] > 0) base[k] = k * CAP2 + atomicAdd(&gcursor[k], cnt[k]);
        __syncthreads();
        for (int e = e0 + t; e < eend; e += 256) {
            int s = src[e], d = dst[e];
            int bk = d >> 6;
            int pos = base[bk] + atomicAdd(&cur[bk], 1);
            if (pos < (bk + 1) * CAP2) pairs[pos] = ((unsigned)s << 6) | (unsigned)(d & 63);
        }
    } else if (blk < 260) {
        int tid = (blk - 196) * 256 + t;    // 0..16383
        int table = tid >> 13;              // 0: W1, 1: W2
        int r = tid & 8191;
        int lane = r & 63, ni = (r >> 6) & 3, ks = (r >> 8) & 7, g = r >> 11;
        int lm = lane & 15, lq = lane >> 4;
        int o = g * 64 + ni * 16 + lm;
        int k = ks * 32 + lq * 8;
        unsigned short v[8];
        if (table == 0) {                   // W1 = [W1l | W1r] K-concat
            if (k < 128) {
#pragma unroll
                for (int j = 0; j < 8; ++j) v[j] = f2bf(W1l[o * 128 + k + j]);
            } else {
#pragma unroll
                for (int j = 0; j < 8; ++j) v[j] = f2bf(W1r[o * 128 + k - 128 + j]);
            }
            *(uint4*)(W1pk + (size_t)r * 8) = *(const uint4*)v;
        } else {                            // W2 = [W2l ; W2r] out-stack
            if (o < 128) {
#pragma unroll
                for (int j = 0; j < 8; ++j) v[j] = f2bf(W2l[o * 256 + k + j]);
            } else {
#pragma unroll
                for (int j = 0; j < 8; ++j) v[j] = f2bf(W2r[(o - 128) * 256 + k + j]);
            }
            *(uint4*)(W2pk + (size_t)r * 8) = *(const uint4*)v;
        }
    } else {
        int gid = (blk - 260) * 256 + t;    // NN*32 threads exactly
        int n = gid >> 5, c = gid & 31;     // self cols k = 128 + c*4 .. +3
        f32x4 v = __builtin_nontemporal_load((const f32x4*)x + (size_t)n * 32 + c);
        unsigned short o[4];
        o[0] = f2bf(v[0]); o[1] = f2bf(v[1]); o[2] = f2bf(v[2]); o[3] = f2bf(v[3]);
        int k = 128 + c * 4;
        int ks = k >> 5, lq = (k >> 3) & 3, j0 = k & 7;
        int tile = n >> 6, r = n & 63, mi = r >> 4, lm = r & 15;
        *(u32x2*)(Apk + (size_t)tile * 16384 +
                  ((size_t)((ks * 4 + mi) * 64 + lm + 16 * lq)) * 8 + j0) = *(const u32x2*)o;
        unsigned p = (unsigned)__builtin_amdgcn_cvt_pk_fp8_f32(v[0], v[1], 0, false);
        p = (unsigned)__builtin_amdgcn_cvt_pk_fp8_f32(v[2], v[3], (int)p, true);
        *(unsigned*)(x_f8 + (size_t)n * 128 + c * 4) = p;
    }
}

// ============ fused CSR build + layer-1 aggregation per 64-node bucket ============
// Sort phase: r5 verbatim. Gather phase widened: 8 threads/node x uint4 loads
// (16B row chunk per lane) — half the vmem instructions per edge, same bytes
// in flight (4-deep x 16B = 64B/thread), same per-column accumulation order.
__global__ __launch_bounds__(512) void k_build_agg1(
        const int* __restrict__ gcursor, const unsigned* __restrict__ pairs,
        const uint4* __restrict__ xf4, unsigned short* __restrict__ esrc,
        unsigned* __restrict__ meta, unsigned short* __restrict__ Apk) {
    __shared__ unsigned lp[CAP2];          // 6 KB pair cache
    __shared__ unsigned short lsrc[CAP2];  // 3 KB sorted src ids
    __shared__ int ldeg[64];
    __shared__ int lcur[64];
    __shared__ int lstart[64];
    int b = blockIdx.x, t = threadIdx.x;
    if (t < 64) ldeg[t] = 0;
    __syncthreads();
    int cnt = min(gcursor[b], CAP2);
    const unsigned* pb = pairs + (size_t)b * CAP2;
    for (int e = t; e < cnt; e += 512) {
        unsigned p = pb[e];
        lp[e] = p;
        atomicAdd(&ldeg[p & 63u], 1);      // int LDS atomic: native ds_add
    }
    __syncthreads();
    if (t < 64) {                          // 64-wide exclusive scan (wave 0, broadcast reads)
        int s = 0;
        for (int j = 0; j < t; ++j) s += ldeg[j];
        lstart[t] = s; lcur[t] = s;
    }
    __syncthreads();
    for (int e = t; e < cnt; e += 512) {
        unsigned p = lp[e];
        int pos = atomicAdd(&lcur[p & 63u], 1);
        lsrc[pos] = (unsigned short)(p >> 6);
    }
    __syncthreads();
    // persist CSR for k_agg_out (bucket-strided esrc; no compaction)
    for (int e = t; e < cnt; e += 512) esrc[(size_t)b * CAP2 + e] = lsrc[e];
    if (t < 64) {
        int node = b * 64 + t;
        if (node < NN)
            meta[node] = ((unsigned)(b * CAP2 + lstart[t])) | ((unsigned)ldeg[t] << 21);
    }
    // ---- aggregation: 8 threads/node, all 64 nodes in one round ----
    int c8 = t & 7, nl = t >> 3;
    {
        int st = lstart[nl], dg = ldeg[nl];
        float acc[16] = {0.f, 0.f, 0.f, 0.f, 0.f, 0.f, 0.f, 0.f,
                         0.f, 0.f, 0.f, 0.f, 0.f, 0.f, 0.f, 0.f};
        int i = 0;
        for (; i + 4 <= dg; i += 4) {
            int s0 = lsrc[st + i],     s1 = lsrc[st + i + 1];
            int s2 = lsrc[st + i + 2], s3 = lsrc[st + i + 3];
            uint4 q0 = xf4[(size_t)s0 * 8 + c8];
            uint4 q1 = xf4[(size_t)s1 * 8 + c8];
            uint4 q2 = xf4[(size_t)s2 * 8 + c8];
            uint4 q3 = xf4[(size_t)s3 * 8 + c8];
            acc_fp8x4(acc, q0); acc_fp8x4(acc, q1);
            acc_fp8x4(acc, q2); acc_fp8x4(acc, q3);
        }
        for (; i < dg; ++i)
            acc_fp8x4(acc, xf4[(size_t)lsrc[st + i] * 8 + c8]);
        float invd = 1.0f / (float)max(dg, 1);
        int mi = nl >> 4, lm = nl & 15;
#pragma unroll
        for (int h = 0; h < 2; ++h) {
            int cc = c8 * 2 + h;           // old 16-wide col-chunk index
            unsigned short o[8];
#pragma unroll
            for (int j = 0; j < 8; ++j) o[j] = f2bf(acc[h * 8 + j] * invd);
            int ks = cc >> 2, lq = cc & 3;
            *(u32x4*)(Apk + (size_t)b * 16384 +
                      ((size_t)((ks * 4 + mi) * 64 + lm + 16 * lq)) * 8) = *(const u32x4*)o;
        }
    }
}

// ============ fused GEMM1(relu)+GEMM2 per 64-node tile, packed-A direct reads ============
// (r5/r10 verbatim — verified absmax 0.0703125)
__global__ __launch_bounds__(256, 2) void k_gemm12(
        const unsigned short* __restrict__ Apk,
        const unsigned short* __restrict__ W1pk, const unsigned short* __restrict__ W2pk,
        const float* __restrict__ b1, const float* __restrict__ b2,
        unsigned char* __restrict__ y2f8, unsigned short* __restrict__ Sbf) {
    __shared__ unsigned short T[16384];   // 32 KB: h tile, then epilogue staging
    int t = threadIdx.x, blk = blockIdx.x;
    int wave = t >> 6, lane = t & 63;
    int lm = lane & 15, lq = lane >> 4;
    int pbase = lm * 4 + lq;

    short8 w[8][4];
    {
        const unsigned short* wb = W1pk + (size_t)wave * 16384;
#pragma unroll
        for (int ks = 0; ks < 8; ++ks)
#pragma unroll
            for (int ni = 0; ni < 4; ++ni)
                w[ks][ni] = *(const short8*)(wb + ((size_t)((ks * 4 + ni) * 64 + lane)) * 8);
    }

    const unsigned short* apk = Apk + (size_t)blk * 16384;
    f32x4 acc1[4][4];
#pragma unroll
    for (int mi = 0; mi < 4; ++mi)
#pragma unroll
        for (int ni = 0; ni < 4; ++ni) acc1[mi][ni] = (f32x4){0.f, 0.f, 0.f, 0.f};
#pragma unroll
    for (int ks = 0; ks < 8; ++ks) {
        short8 a[4];
#pragma unroll
        for (int mi = 0; mi < 4; ++mi)
            a[mi] = *(const short8*)(apk + ((size_t)((ks * 4 + mi) * 64 + lane)) * 8);
#pragma unroll
        for (int mi = 0; mi < 4; ++mi)
#pragma unroll
            for (int ni = 0; ni < 4; ++ni)
                acc1[mi][ni] = __builtin_amdgcn_mfma_f32_16x16x32_bf16(a[mi], w[ks][ni], acc1[mi][ni], 0, 0, 0);
    }

    {
        const unsigned short* wb = W2pk + (size_t)wave * 16384;
#pragma unroll
        for (int ks = 0; ks < 8; ++ks)
#pragma unroll
            for (int ni = 0; ni < 4; ++ni)
                w[ks][ni] = *(const short8*)(wb + ((size_t)((ks * 4 + ni) * 64 + lane)) * 8);
    }

#pragma unroll
    for (int ni = 0; ni < 4; ++ni) {
        int col = wave * 64 + ni * 16 + lm;
        float bv = b1[col];
        int ks = col >> 5;
        int la = (col & 31) >> 3, j = col & 7;
#pragma unroll
        for (int mi = 0; mi < 4; ++mi)
#pragma unroll
            for (int r = 0; r < 4; ++r) {
                float v = fmaxf(acc1[mi][ni][r] + bv, 0.0f);
                T[((size_t)((ks * 4 + mi) * 64 + (lq * 4 + r) * 4 + la)) * 8 + j] = f2bf(v);
            }
    }
    __syncthreads();

    f32x4 acc2[4][4];
#pragma unroll
    for (int mi = 0; mi < 4; ++mi)
#pragma unroll
        for (int ni = 0; ni < 4; ++ni) acc2[mi][ni] = (f32x4){0.f, 0.f, 0.f, 0.f};
#pragma unroll
    for (int ks = 0; ks < 8; ++ks) {
        short8 a[4];
#pragma unroll
        for (int mi = 0; mi < 4; ++mi)
            a[mi] = *(const short8*)(T + ((size_t)((ks * 4 + mi) * 64 + pbase)) * 8);
#pragma unroll
        for (int mi = 0; mi < 4; ++mi)
#pragma unroll
            for (int ni = 0; ni < 4; ++ni)
                acc2[mi][ni] = __builtin_amdgcn_mfma_f32_16x16x32_bf16(a[mi], w[ks][ni], acc2[mi][ni], 0, 0, 0);
    }
    __syncthreads();

    {
        unsigned char* T8 = (unsigned char*)T;
        unsigned short* T16 = (unsigned short*)T + 4096;
        if (wave < 2) {
#pragma unroll
            for (int ni = 0; ni < 4; ++ni) {
                int col = wave * 64 + ni * 16 + lm;
#pragma unroll
                for (int mi = 0; mi < 4; ++mi)
#pragma unroll
                    for (int r = 0; r < 4; ++r) {
                        int rl = mi * 16 + lq * 4 + r;
                        float v = acc2[mi][ni][r];
                        unsigned p = (unsigned)__builtin_amdgcn_cvt_pk_fp8_f32(v, v, 0, false);
                        T8[rl * 128 + col] = (unsigned char)(p & 0xff);
                    }
            }
        } else {
#pragma unroll
            for (int ni = 0; ni < 4; ++ni) {
                int col = (wave - 2) * 64 + ni * 16 + lm;
                float bv = b2[col];
#pragma unroll
                for (int mi = 0; mi < 4; ++mi)
#pragma unroll
                    for (int r = 0; r < 4; ++r) {
                        int rl = mi * 16 + lq * 4 + r;
                        T16[rl * 128 + col] = f2bf(acc2[mi][ni][r] + bv);
                    }
            }
        }
    }
    __syncthreads();

    {
        const uint4* Ty = (const uint4*)T;
        uint4* gy = (uint4*)(y2f8 + (size_t)blk * 64 * 128);
        gy[t] = Ty[t];
        gy[t + 256] = Ty[t + 256];
        const u32x4* Ts = (const u32x4*)((const char*)T + 8192);
        u32x4* gs = (u32x4*)(Sbf + (size_t)blk * 64 * 128);
#pragma unroll
        for (int i = 0; i < 4; ++i)
            __builtin_nontemporal_store(Ts[t + i * 256], &gs[t + i * 256]);
    }
}

// ============ output: out[n] = Sbf[n] + mean_nbr(y2f8) ============
// 8 threads/node x uint4 gather loads (16B row chunk per lane): half the vmem
// instructions vs r5's uint2 form; 64B contiguous f32 output per thread.
__global__ void k_agg_out(const uint4* __restrict__ yf4, const unsigned short* __restrict__ Sbf,
                          const unsigned* __restrict__ meta,
                          const unsigned short* __restrict__ esrc,
                          float* __restrict__ out) {
    int gid = blockIdx.x * blockDim.x + threadIdx.x;
    if (gid >= NN * 8) return;
    int n = gid >> 3, c8 = gid & 7;
    unsigned mt = meta[n];
    int st = (int)(mt & 0x1FFFFFu), dg = (int)(mt >> 21);
    float acc[16] = {0.f, 0.f, 0.f, 0.f, 0.f, 0.f, 0.f, 0.f,
                     0.f, 0.f, 0.f, 0.f, 0.f, 0.f, 0.f, 0.f};
    int i = 0;
    for (; i + 4 <= dg; i += 4) {
        int s0 = esrc[st + i],     s1 = esrc[st + i + 1];
        int s2 = esrc[st + i + 2], s3 = esrc[st + i + 3];
        uint4 q0 = yf4[(size_t)s0 * 8 + c8];
        uint4 q1 = yf4[(size_t)s1 * 8 + c8];
        uint4 q2 = yf4[(size_t)s2 * 8 + c8];
        uint4 q3 = yf4[(size_t)s3 * 8 + c8];
        acc_fp8x4(acc, q0); acc_fp8x4(acc, q1);
        acc_fp8x4(acc, q2); acc_fp8x4(acc, q3);
    }
    for (; i < dg; ++i)
        acc_fp8x4(acc, yf4[(size_t)esrc[st + i] * 8 + c8]);
    float invd = 1.0f / (float)max(dg, 1);
    const u32x4* sb = (const u32x4*)Sbf + (size_t)n * 16 + c8 * 2;
    u32x4 sv0 = __builtin_nontemporal_load(sb);
    u32x4 sv1 = __builtin_nontemporal_load(sb + 1);
    f32x4 o0, o1, o2, o3;
    o0[0] = bfu_lo(sv0[0]) + acc[0]  * invd; o0[1] = bfu_hi(sv0[0]) + acc[1]  * invd;
    o0[2] = bfu_lo(sv0[1]) + acc[2]  * invd; o0[3] = bfu_hi(sv0[1]) + acc[3]  * invd;
    o1[0] = bfu_lo(sv0[2]) + acc[4]  * invd; o1[1] = bfu_hi(sv0[2]) + acc[5]  * invd;
    o1[2] = bfu_lo(sv0[3]) + acc[6]  * invd; o1[3] = bfu_hi(sv0[3]) + acc[7]  * invd;
    o2[0] = bfu_lo(sv1[0]) + acc[8]  * invd; o2[1] = bfu_hi(sv1[0]) + acc[9]  * invd;
    o2[2] = bfu_lo(sv1[1]) + acc[10] * invd; o2[3] = bfu_hi(sv1[1]) + acc[11] * invd;
    o3[0] = bfu_lo(sv1[2]) + acc[12] * invd; o3[1] = bfu_hi(sv1[2]) + acc[13] * invd;
    o3[2] = bfu_lo(sv1[3]) + acc[14] * invd; o3[3] = bfu_hi(sv1[3]) + acc[15] * invd;
    f32x4* op = (f32x4*)(out + (size_t)n * 128 + c8 * 16);
    __builtin_nontemporal_store(o0, op);
    __builtin_nontemporal_store(o1, op + 1);
    __builtin_nontemporal_store(o2, op + 2);
    __builtin_nontemporal_store(o3, op + 3);
}

extern "C" void kernel_launch(void* const* d_in, const int* in_sizes, int n_in,
                              void* d_out, int out_size, void* d_ws, size_t ws_size,
                              hipStream_t stream) {
    const float* x   = (const float*)d_in[0];
    const int*   ei  = (const int*)d_in[1];
    const int*   src = ei;
    const int*   dst = ei + NE;
    const float* W1l = (const float*)d_in[2];
    const float* b1  = (const float*)d_in[3];
    const float* W1r = (const float*)d_in[4];
    const float* W2l = (const float*)d_in[5];
    const float* b2  = (const float*)d_in[6];
    const float* W2r = (const float*)d_in[7];
    float* out = (float*)d_out;

    // workspace layout (~59 MB):
    char* ws = (char*)d_ws;
    int* gcursor          = (int*)(ws + 0);                    // [784] bucket counts
    unsigned* meta        = (unsigned*)(ws + 4096);            // [NN_PAD] start|deg<<21
    unsigned* pairs       = (unsigned*)(ws + 204800);          // [784*1536] 4.8 MB
    unsigned short* esrc  = (unsigned short*)(ws + 5021696);   // [784*1536] 2.4 MB
    unsigned char* x_f8   = (unsigned char*)(ws + 7430144);    // [NN,128] fp8 6.4 MB
    unsigned short* Sbf   = (unsigned short*)(ws + 13830144);  // [NN_PAD,128] bf16 12.85 MB
    unsigned char* y2f8   = (unsigned char*)(ws + 26675200);   // [NN_PAD,128] fp8 6.42 MB
    unsigned short* Apk   = (unsigned short*)(ws + 33097728);  // [NN_PAD,256] bf16 frag-packed
    unsigned short* W1pk  = (unsigned short*)(ws + 58787840);  // [65536] 131 KB frag-packed
    unsigned short* W2pk  = (unsigned short*)(ws + 58918912);  // [65536] 131 KB frag-packed

    hipMemsetAsync(gcursor, 0, 4096, stream);
    k_setup_part<<<6510, 256, 0, stream>>>(W1l, W1r, W2l, W2r, W1pk, W2pk,
                                           x, Apk, x_f8, src, dst, gcursor, pairs);
    k_build_agg1<<<NB2, 512, 0, stream>>>(gcursor, pairs, (const uint4*)x_f8,
                                          esrc, meta, Apk);
    k_gemm12<<<NB2, 256, 0, stream>>>(Apk, W1pk, W2pk, b1, b2, y2f8, Sbf);
    k_agg_out<<<(NN * 8 + 255) / 256, 256, 0, stream>>>((const uint4*)y2f8, Sbf,
                                                        meta, esrc, out);
}